// Round 2
// baseline (884.738 us; speedup 1.0000x reference)
//
#include <hip/hip_runtime.h>
#include <hip/hip_bf16.h>

// VQ-VAE forward loss on MI355X.
// loss = 2.25 * mean((emb[argmin] - x)^2)
//      = 2.25/(N*D) * [ sum(x^2) + sum_n min_k(||e_k||^2 - 2 x_n.e_k) ]
// GEMM part (x . e_k) in bf16 MFMA; ||x||^2, ||e||^2 exact fp32.
//
// R4: LDS-traffic cut. R3's counters showed LDS reads were the largest pipe
// (4 GB: every one of 16 waves re-read the whole x tile). Changes:
//  - mfma 32x32x16 (Ra=2 rowtiles x Cb=2 coltiles per wave): 1/32 B/MAC from
//    LDS (2x less), 4x fewer MFMA instructions. acc = 2x2 f32x16 = 64 AGPR.
//  - 8 waves (NT=512), 64 codes/wave: LDS_A = 2.01 GB total (~50 us pipe).
//  - __launch_bounds__(512,4) -> <=128 regs -> 4 waves/SIMD -> 2 blocks/CU,
//    blocks run in anti-phase to overlap staging vs compute.
//  - Keep R3 chunk pipeline: BK=96, LDS double buffer, issue-early/write-late,
//    one barrier per chunk; B frags register-double-buffered from L2.

#define NROWS (64 * 4096)   // 262144
#define DDIM  480
#define KCODES 512
#define BM    64            // rows per block
#define BK    96            // k-chunk: 6 MFMA k-steps of 16
#define NCH   5             // 480 / 96
#define LDSP  104           // padded chunk row stride (bf16): 96 + 8 (52 dwords, uniform banks)
#define NT    512           // threads per block (8 waves)

typedef __bf16 bf16x8 __attribute__((ext_vector_type(8)));
typedef float  f32x16 __attribute__((ext_vector_type(16)));

__device__ __forceinline__ ushort f2bf(float v) {
    union { float f; unsigned u; } c; c.f = v;
    unsigned u = c.u;
    u += 0x7fffu + ((u >> 16) & 1u);   // round-to-nearest-even
    return (ushort)(u >> 16);
}

// Convert codebook to bf16 in ws, compute ||e_k||^2 (fp32 exact), zero d_out.
__global__ void vq_setup(const float* __restrict__ e, ushort* __restrict__ ebf,
                         float* __restrict__ esq, float* __restrict__ out) {
    const int k = blockIdx.x;   // one code row per block (1 wave)
    const int t = threadIdx.x;
    if (k == 0 && t == 0) out[0] = 0.0f;
    float s = 0.0f;
    for (int d = t; d < DDIM; d += 64) {
        float v = e[k * DDIM + d];
        s += v * v;
        ebf[k * DDIM + d] = f2bf(v);
    }
    #pragma unroll
    for (int m = 32; m >= 1; m >>= 1) s += __shfl_xor(s, m, 64);
    if (t == 0) esq[k] = s;
}

__global__ __launch_bounds__(NT, 4) void vq_main(const float* __restrict__ x,
        const ushort* __restrict__ ebf, const float* __restrict__ esq,
        float* __restrict__ out) {
    __shared__ ushort xs[2][BM * LDSP];   // 2 x 13312 B = 26624 B
    __shared__ float red[8 * BM];         // per-wave per-row mins
    __shared__ float redw[8];

    const int t    = threadIdx.x;
    const int wave = t >> 6;
    const int lane = t & 63;
    const int l31  = lane & 31;   // 32x32 MFMA row/col lane index
    const int hw   = lane >> 5;   // k-half

    const float* xb = x + (size_t)blockIdx.x * (BM * DDIM);

    // ---- staging map: chunk = 64 rows x 24 float4 = 1536 float4; 3/thread ----
    const int f0 = t;            const int r0 = f0 / 24, c0f = (f0 % 24) * 4;
    const int f1 = t + NT;       const int r1 = f1 / 24, c1f = (f1 % 24) * 4;
    const int f2 = t + 2 * NT;   const int r2 = f2 / 24, c2f = (f2 % 24) * 4;

    const float* g0 = xb + r0 * DDIM + c0f;
    const float* g1 = xb + r1 * DDIM + c1f;
    const float* g2 = xb + r2 * DDIM + c2f;
    const int l0 = r0 * LDSP + c0f;
    const int l1 = r1 * LDSP + c1f;
    const int l2 = r2 * LDSP + c2f;

    float xsq = 0.0f;

    // ---- prologue: stage chunk 0 into xs[0] ----
    {
        float4 v0 = *(const float4*)g0;
        float4 v1 = *(const float4*)g1;
        float4 v2 = *(const float4*)g2;
        xsq += v0.x * v0.x + v0.y * v0.y + v0.z * v0.z + v0.w * v0.w;
        xsq += v1.x * v1.x + v1.y * v1.y + v1.z * v1.z + v1.w * v1.w;
        xsq += v2.x * v2.x + v2.y * v2.y + v2.z * v2.z + v2.w * v2.w;
        ushort4 b;
        b.x = f2bf(v0.x); b.y = f2bf(v0.y); b.z = f2bf(v0.z); b.w = f2bf(v0.w);
        *(ushort4*)(&xs[0][l0]) = b;
        b.x = f2bf(v1.x); b.y = f2bf(v1.y); b.z = f2bf(v1.z); b.w = f2bf(v1.w);
        *(ushort4*)(&xs[0][l1]) = b;
        b.x = f2bf(v2.x); b.y = f2bf(v2.y); b.z = f2bf(v2.z); b.w = f2bf(v2.w);
        *(ushort4*)(&xs[0][l2]) = b;
    }

    // ---- per-wave code slice: 64 codes = 2 coltiles of 32 ----
    const int code0 = wave * 64;
    // B fragment: lane (l31,hw) reads code (code0 + c*32 + l31), k = hw*8 + dk*16
    const ushort* bp0 = ebf + (size_t)(code0 + l31) * DDIM + hw * 8;
    const ushort* bp1 = bp0 + (size_t)32 * DDIM;

    f32x16 acc[2][2];   // [rowtile][coltile]
    #pragma unroll
    for (int r = 0; r < 2; ++r)
        #pragma unroll
        for (int c = 0; c < 2; ++c)
            #pragma unroll
            for (int j = 0; j < 16; ++j) acc[r][c][j] = 0.f;

    bf16x8 Bb[2][2];    // [dk parity][coltile], register double buffer
    Bb[0][0] = *(const bf16x8*)bp0;
    Bb[0][1] = *(const bf16x8*)bp1;

    __syncthreads();

    // ---- main pipeline: 5 chunks, compute cur while staging next ----
    #pragma unroll
    for (int t5 = 0; t5 < NCH; ++t5) {
        float4 v0, v1, v2;
        if (t5 < NCH - 1) {   // issue next chunk's loads EARLY
            v0 = *(const float4*)(g0 + (t5 + 1) * BK);
            v1 = *(const float4*)(g1 + (t5 + 1) * BK);
            v2 = *(const float4*)(g2 + (t5 + 1) * BK);
        }
        #pragma unroll
        for (int kk = 0; kk < 6; ++kk) {      // 6 k-steps of 16 per chunk
            const int dk = t5 * 6 + kk;
            const int pc = dk & 1;
            if (dk < 29) {   // prefetch B for next k-step (crosses chunk edge)
                Bb[pc ^ 1][0] = *(const bf16x8*)(bp0 + (dk + 1) * 16);
                Bb[pc ^ 1][1] = *(const bf16x8*)(bp1 + (dk + 1) * 16);
            }
            bf16x8 A0 = *(const bf16x8*)(&xs[t5 & 1][l31 * LDSP + kk * 16 + hw * 8]);
            bf16x8 A1 = *(const bf16x8*)(&xs[t5 & 1][(32 + l31) * LDSP + kk * 16 + hw * 8]);
            acc[0][0] = __builtin_amdgcn_mfma_f32_32x32x16_bf16(A0, Bb[pc][0], acc[0][0], 0, 0, 0);
            acc[0][1] = __builtin_amdgcn_mfma_f32_32x32x16_bf16(A0, Bb[pc][1], acc[0][1], 0, 0, 0);
            acc[1][0] = __builtin_amdgcn_mfma_f32_32x32x16_bf16(A1, Bb[pc][0], acc[1][0], 0, 0, 0);
            acc[1][1] = __builtin_amdgcn_mfma_f32_32x32x16_bf16(A1, Bb[pc][1], acc[1][1], 0, 0, 0);
        }
        if (t5 < NCH - 1) {   // convert + ds_write LATE, into the other buffer
            xsq += v0.x * v0.x + v0.y * v0.y + v0.z * v0.z + v0.w * v0.w;
            xsq += v1.x * v1.x + v1.y * v1.y + v1.z * v1.z + v1.w * v1.w;
            xsq += v2.x * v2.x + v2.y * v2.y + v2.z * v2.z + v2.w * v2.w;
            ushort4 b;
            const int nb = (t5 & 1) ^ 1;
            b.x = f2bf(v0.x); b.y = f2bf(v0.y); b.z = f2bf(v0.z); b.w = f2bf(v0.w);
            *(ushort4*)(&xs[nb][l0]) = b;
            b.x = f2bf(v1.x); b.y = f2bf(v1.y); b.z = f2bf(v1.z); b.w = f2bf(v1.w);
            *(ushort4*)(&xs[nb][l1]) = b;
            b.x = f2bf(v2.x); b.y = f2bf(v2.y); b.z = f2bf(v2.z); b.w = f2bf(v2.w);
            *(ushort4*)(&xs[nb][l2]) = b;
        }
        __syncthreads();   // one barrier per chunk
    }

    // ---- fold: min_k (esq[k] - 2*dot) ----
    // acc[r][c][j]: row = r*32 + (j&3) + 8*(j>>2) + 4*hw, col(code) = code0 + c*32 + l31
    float rmin[2][16];
    #pragma unroll
    for (int r = 0; r < 2; ++r)
        #pragma unroll
        for (int j = 0; j < 16; ++j) rmin[r][j] = 1e30f;
    #pragma unroll
    for (int c = 0; c < 2; ++c) {
        float es = esq[code0 + c * 32 + l31];
        #pragma unroll
        for (int r = 0; r < 2; ++r)
            #pragma unroll
            for (int j = 0; j < 16; ++j)
                rmin[r][j] = fminf(rmin[r][j], es - 2.0f * acc[r][c][j]);
    }

    // ---- cross-lane min over the 32 col lanes (bits 0..4, stays in half-wave) ----
    #pragma unroll
    for (int r = 0; r < 2; ++r)
        #pragma unroll
        for (int j = 0; j < 16; ++j) {
            float v = rmin[r][j];
            v = fminf(v, __shfl_xor(v, 1, 64));
            v = fminf(v, __shfl_xor(v, 2, 64));
            v = fminf(v, __shfl_xor(v, 4, 64));
            v = fminf(v, __shfl_xor(v, 8, 64));
            v = fminf(v, __shfl_xor(v, 16, 64));
            if (l31 == 0)
                red[wave * 64 + r * 32 + (j & 3) + 8 * (j >> 2) + 4 * hw] = v;
        }
    __syncthreads();

    // ---- combine: min across 8 waves per row, + sum(x^2), block reduce ----
    float val = xsq;
    if (t < 64) {
        float m0 = fminf(red[t],       red[64 + t]);
        float m1 = fminf(red[128 + t], red[192 + t]);
        float m2 = fminf(red[256 + t], red[320 + t]);
        float m3 = fminf(red[384 + t], red[448 + t]);
        val += fminf(fminf(m0, m1), fminf(m2, m3));
    }
    #pragma unroll
    for (int m = 32; m >= 1; m >>= 1) val += __shfl_xor(val, m, 64);
    if (lane == 0) redw[wave] = val;
    __syncthreads();
    if (t == 0) {
        const float SCALE = 2.25f / ((float)NROWS * (float)DDIM);
        float s = 0.f;
        #pragma unroll
        for (int w = 0; w < 8; ++w) s += redw[w];
        atomicAdd(out, s * SCALE);
    }
}

extern "C" void kernel_launch(void* const* d_in, const int* in_sizes, int n_in,
                              void* d_out, int out_size, void* d_ws, size_t ws_size,
                              hipStream_t stream) {
    (void)in_sizes; (void)n_in; (void)out_size; (void)ws_size;
    const float* x = (const float*)d_in[0];   // [262144, 480] fp32
    const float* e = (const float*)d_in[1];   // [512, 480] fp32
    float* out = (float*)d_out;               // scalar fp32
    ushort* ebf = (ushort*)d_ws;                              // 512*480*2 = 491520 B
    float*  esq = (float*)((char*)d_ws + KCODES * DDIM * 2);  // 512*4 B

    vq_setup<<<KCODES, 64, 0, stream>>>(e, ebf, esq, out);
    vq_main<<<NROWS / BM, NT, 0, stream>>>(x, ebf, esq, out);
}